// Round 22
// baseline (473.984 us; speedup 1.0000x reference)
//
#include <hip/hip_runtime.h>

// Emformer convolution module, MI355X/gfx950.
// Pipeline: cast weights -> LN1 -> GEMM1+GLU (bf16 MFMA) -> dwconv+LN2+SiLU (+state emit) -> GEMM2+residual.
// R7: __syncthreads drains vmcnt(0). R8: dbuf halves occupancy -> TLP wins (128^2/2-phase).
// R10: LDS swizzle -> bank conflicts 0. R16: min-waves squeezes VGPR -> spill.
// R20 WIN: gemm2 nt-epilogue + state fused into conv. 351.5us.
// R21: conv (256,3) neutral - occupancy stuck at 2 blocks/CU: LDS-bound (47.6KB/block).
// R22: conv split staging: 46-row window consumed in two 23-row chunks through one 23.5KB
//   buffer (each row consumed exactly once); LDS 47.6 -> 32.9KB -> 4 blocks/CU, waves 8 -> 16.

#define Dm 512
#define STATE 30
#define Uu 2048
#define Rr 512
#define Bb 32
#define Tt 2560        // Rr + Uu
#define MROWS 81920    // Tt * Bb

typedef unsigned short u16;
typedef unsigned int u32;
typedef __attribute__((ext_vector_type(8))) __bf16 bf16x8;
typedef __attribute__((ext_vector_type(4))) float f32x4;
typedef __attribute__((ext_vector_type(2))) float f32x2;

__device__ __forceinline__ u16 f2bf(float x) {
  u32 u = __float_as_uint(x);
  u += 0x7fff + ((u >> 16) & 1);   // RNE
  return (u16)(u >> 16);
}
__device__ __forceinline__ float bf2f(u16 h) {
  return __uint_as_float((u32)h << 16);
}
__device__ __forceinline__ void load_lds16(const void* g, void* l) {
  __builtin_amdgcn_global_load_lds(
      (const __attribute__((address_space(1))) void*)g,
      (__attribute__((address_space(3))) void*)l, 16, 0, 0);
}

// ---------------- cast f32 -> bf16 (weights) ----------------
__global__ __launch_bounds__(256, 4) void k_cast(const float* __restrict__ src,
                                                 u16* __restrict__ dst, int n) {
  int i = (blockIdx.x * 256 + threadIdx.x) * 4;
  if (i >= n) return;
  float4 v = *(const float4*)(src + i);
  u32 lo = (u32)f2bf(v.x) | ((u32)f2bf(v.y) << 16);
  u32 hi = (u32)f2bf(v.z) | ((u32)f2bf(v.w) << 16);
  *(uint2*)(dst + i) = make_uint2(lo, hi);
}

// ---------------- transpose conv weight: cw[512][31] -> cwT[31][512] ----------------
__global__ __launch_bounds__(256, 4) void k_wt(const float* __restrict__ cw,
                                               float* __restrict__ cwT) {
  int i = blockIdx.x * 256 + threadIdx.x;
  if (i >= 31 * 512) return;
  int k = i >> 9, d = i & 511;
  cwT[i] = cw[d * 31 + k];
}

// ---------------- LN1: concat(rc, utt) -> bf16 ----------------
__global__ __launch_bounds__(256, 4) void k_ln1(const float* __restrict__ utt,
                                                const float* __restrict__ rc,
                                                const float* __restrict__ g,
                                                const float* __restrict__ b,
                                                u16* __restrict__ out) {
  int wid = threadIdx.x >> 6, lane = threadIdx.x & 63;
  long row = (long)blockIdx.x * 4 + wid;  // token index tau = t*B + b
  const float* src = (row < (long)Rr * Bb) ? rc + row * Dm
                                           : utt + (row - (long)Rr * Bb) * Dm;
  int d0 = lane * 8;
  float4 v0 = *(const float4*)(src + d0);
  float4 v1 = *(const float4*)(src + d0 + 4);
  float s = v0.x + v0.y + v0.z + v0.w + v1.x + v1.y + v1.z + v1.w;
  float ss = v0.x * v0.x + v0.y * v0.y + v0.z * v0.z + v0.w * v0.w +
             v1.x * v1.x + v1.y * v1.y + v1.z * v1.z + v1.w * v1.w;
#pragma unroll
  for (int off = 1; off < 64; off <<= 1) {
    s += __shfl_xor(s, off);
    ss += __shfl_xor(ss, off);
  }
  float mean = s * (1.f / 512.f);
  float var = ss * (1.f / 512.f) - mean * mean;
  float rstd = rsqrtf(var + 1e-5f);
  float4 g0 = *(const float4*)(g + d0);
  float4 g1 = *(const float4*)(g + d0 + 4);
  float4 b0 = *(const float4*)(b + d0);
  float4 b1v = *(const float4*)(b + d0 + 4);
  float o[8];
  o[0] = (v0.x - mean) * rstd * g0.x + b0.x;
  o[1] = (v0.y - mean) * rstd * g0.y + b0.y;
  o[2] = (v0.z - mean) * rstd * g0.z + b0.z;
  o[3] = (v0.w - mean) * rstd * g0.w + b0.w;
  o[4] = (v1.x - mean) * rstd * g1.x + b1v.x;
  o[5] = (v1.y - mean) * rstd * g1.y + b1v.y;
  o[6] = (v1.z - mean) * rstd * g1.z + b1v.z;
  o[7] = (v1.w - mean) * rstd * g1.w + b1v.w;
  u32 p[4];
#pragma unroll
  for (int i = 0; i < 4; ++i)
    p[i] = (u32)f2bf(o[2 * i]) | ((u32)f2bf(o[2 * i + 1]) << 16);
  *(uint4*)(out + row * Dm + d0) = make_uint4(p[0], p[1], p[2], p[3]);
}

// ---------------- GEMM1 + GLU (1-phase BK=64, swizzled LDS) ----------------
__global__ __launch_bounds__(256, 2) void k_gemm1(const u16* __restrict__ A,
                                                  const u16* __restrict__ Wb,
                                                  const float* __restrict__ b1,
                                                  u16* __restrict__ X) {
  __shared__ __align__(16) u16 sA[128 * 64], sBa[128 * 64], sBg[128 * 64];
  int tid = threadIdx.x;
  int bid = blockIdx.x;
  int bm = bid >> 2, nt = bid & 3;
  long arow0 = (long)bm * 128;
  int ncol0 = nt * 128;
  int lane = tid & 63, wid = tid >> 6;
  int wm = (wid >> 1) * 64, wn = (wid & 1) * 64;
  int lr = lane & 15, kg = lane >> 4;
  int l7 = lr & 7;

  f32x4 acc_a[4][4], acc_g[4][4];
#pragma unroll
  for (int i = 0; i < 4; ++i)
#pragma unroll
    for (int j = 0; j < 4; ++j) {
      acc_a[i][j] = (f32x4)0.f;
      acc_g[i][j] = (f32x4)0.f;
    }

  for (int k0 = 0; k0 < 512; k0 += 64) {
#pragma unroll
    for (int i = 0; i < 4; ++i) {
      int c = i * 256 + tid;
      int r = c >> 3;
      int col = ((c & 7) ^ (r & 7)) * 8;  // pre-swizzled source column
      load_lds16(A + (arow0 + r) * 512 + k0 + col, &sA[c * 8]);
      load_lds16(Wb + (long)(ncol0 + r) * 512 + k0 + col, &sBa[c * 8]);
      load_lds16(Wb + (long)(512 + ncol0 + r) * 512 + k0 + col, &sBg[c * 8]);
    }
    __syncthreads();
#pragma unroll
    for (int kf = 0; kf < 2; ++kf) {
      int u = (kf * 4 + kg) ^ l7;  // swizzled read unit
      bf16x8 av[4], bav[4], bgv[4];
#pragma unroll
      for (int i = 0; i < 4; ++i) {
        av[i] = *(const bf16x8*)&sA[(wm + i * 16 + lr) * 64 + u * 8];
        bav[i] = *(const bf16x8*)&sBa[(wn + i * 16 + lr) * 64 + u * 8];
        bgv[i] = *(const bf16x8*)&sBg[(wn + i * 16 + lr) * 64 + u * 8];
      }
#pragma unroll
      for (int mi = 0; mi < 4; ++mi)
#pragma unroll
        for (int ni = 0; ni < 4; ++ni) {
          acc_a[mi][ni] = __builtin_amdgcn_mfma_f32_16x16x32_bf16(
              av[mi], bav[ni], acc_a[mi][ni], 0, 0, 0);
          acc_g[mi][ni] = __builtin_amdgcn_mfma_f32_16x16x32_bf16(
              av[mi], bgv[ni], acc_g[mi][ni], 0, 0, 0);
        }
    }
    __syncthreads();
  }
  int mg = kg * 4;
#pragma unroll
  for (int mi = 0; mi < 4; ++mi) {
#pragma unroll
    for (int ni = 0; ni < 4; ++ni) {
      int ncol = ncol0 + wn + ni * 16 + lr;
      float ba = b1[ncol], bg = b1[512 + ncol];
#pragma unroll
      for (int rgi = 0; rgi < 4; ++rgi) {
        long row = arow0 + wm + mi * 16 + mg + rgi;
        float a = acc_a[mi][ni][rgi] + ba;
        float gg = acc_g[mi][ni][rgi] + bg;
        float val = a / (1.f + __expf(-gg));
        X[row * 512 + ncol] = f2bf(val);
      }
    }
  }
}

// ---------------- depthwise conv + LN2 + SiLU + state emit (split staging) ----------------
// grid (160, 32), 256 threads: thread t owns channels {2t, 2t+1}. Packed f32x2 math.
// Window processed in two 23-row chunks through one 23.5KB buffer; LDS 32.9KB -> 4 blocks/CU.
__global__ __launch_bounds__(256, 4) void k_conv_ln2(
    const u16* __restrict__ X, const float* __restrict__ state,
    const float* __restrict__ cwT, const float* __restrict__ cb,
    const float* __restrict__ g2, const float* __restrict__ bt2,
    u16* __restrict__ Z, float* __restrict__ st_out) {
  __shared__ __align__(16) u16 stX[16 * 512 * 2];  // 32768 B: stage chunk (23*512 u16) | ys alias
  __shared__ float stats[16][2];
  float* ys = (float*)stX;

  int t = threadIdx.x;            // 0..255
  int d0 = t * 2;                 // channel pair
  int tile = blockIdx.x, b = blockIdx.y;
  int wv = t >> 6, ln = t & 63;   // 4 waves

  f32x2 w[31];
#pragma unroll
  for (int k = 0; k < 31; ++k) w[k] = *(const f32x2*)&cwT[k * 512 + d0];  // coalesced
  f32x2 acc[16];
  {
    f32x2 cb2 = *(const f32x2*)&cb[d0];
#pragma unroll
    for (int r = 0; r < 16; ++r) acc[r] = cb2;
  }

  auto step = [&](int j, f32x2 x) {
#pragma unroll
    for (int r = 0; r < 16; ++r) {
      int k = j - r;
      if (k >= 0 && k < 31) acc[r] += x * w[k];   // packed fma
    }
  };
  auto unpack = [](u32 xx) -> f32x2 {
    f32x2 v;
    v.x = __uint_as_float(xx << 16);
    v.y = __uint_as_float(xx & 0xffff0000u);
    return v;
  };

  const u16* Xb = X + (long)b * 512;  // + trow*16384 + col

  if (tile >= 2) {
    // row (0..45) -> global token row, per tile class
    auto trow_of = [&](int row) -> long {
      if (tile < 128) {
        return (long)Rr + tile * 16 - 30 + row;
      } else if (tile < 144) {
        int s = tile - 128;
        return (row < 30) ? ((long)Rr + 128 * (s + 1) - 30 + row)
                          : ((long)32 * s + row - 30);
      } else {
        int s = tile - 144;
        return (row < 14) ? ((long)Rr + 128 * (s + 1) - 14 + row)
                          : ((long)32 * s + row - 14);
      }
    };
    // ---- chunk A: rows 0..22 -> slots 0..22 ----
    for (int r = wv; r < 23; r += 4)
      load_lds16(Xb + trow_of(r) * 16384 + ln * 8, &stX[r * 512 + ln * 8]);
    __syncthreads();
#pragma unroll
    for (int j = 0; j < 23; ++j) {
      u32 xx = *(const u32*)&stX[j * 512 + d0];
      step(j, unpack(xx));
      if ((j & 7) == 7) __builtin_amdgcn_sched_barrier(0);
    }
    if (tile == 127) {  // state rows 16..22 (slots 16..22) -> st_out j 0..6
      float* s0 = st_out + ((long)b * 512 + d0) * 30;
      float* s1 = s0 + 30;
#pragma unroll
      for (int j = 0; j < 7; ++j) {
        u32 xx = *(const u32*)&stX[(16 + j) * 512 + d0];
        s0[j] = __uint_as_float(xx << 16);
        s1[j] = __uint_as_float(xx & 0xffff0000u);
      }
    }
    __syncthreads();  // chunk A fully read before overwrite
    // ---- chunk B: rows 23..45 -> slots 0..22 ----
    for (int r = wv; r < 23; r += 4)
      load_lds16(Xb + trow_of(23 + r) * 16384 + ln * 8, &stX[r * 512 + ln * 8]);
    __syncthreads();
#pragma unroll
    for (int j = 23; j < 46; ++j) {
      u32 xx = *(const u32*)&stX[(j - 23) * 512 + d0];
      step(j, unpack(xx));
      if ((j & 7) == 7) __builtin_amdgcn_sched_barrier(0);
    }
    if (tile == 127) {  // state rows 23..45 (slots 0..22) -> st_out j 7..29
      float* s0 = st_out + ((long)b * 512 + d0) * 30;
      float* s1 = s0 + 30;
#pragma unroll
      for (int j = 7; j < 30; ++j) {
        u32 xx = *(const u32*)&stX[(j - 7) * 512 + d0];
        s0[j] = __uint_as_float(xx << 16);
        s1[j] = __uint_as_float(xx & 0xffff0000u);
      }
    }
  } else {
    // tiles 0..1: window reaches before utterance start (global path, unchanged)
    long t0 = (long)tile * 16;
    const float* st0 = state + ((long)b * 512 + d0) * 30;
    const float* st1 = st0 + 30;
    const u16* Xc = Xb + d0;
#pragma unroll
    for (int j = 0; j < 46; ++j) {
      long tj = t0 - 30 + j;
      f32x2 x;
      if (tj < 0) {
        x.x = st0[tj + 30];
        x.y = st1[tj + 30];
      } else {
        x = unpack(*(const u32*)&Xc[((long)Rr + tj) * 16384]);
      }
      step(j, x);
      if ((j & 15) == 15) __builtin_amdgcn_sched_barrier(0);
    }
  }

  __syncthreads();  // all stX reads done before ys overwrites it
#pragma unroll
  for (int r = 0; r < 16; ++r) {
    *(f32x2*)&ys[r * 512 + d0] = acc[r];
  }
  __syncthreads();

#pragma unroll
  for (int rr = 0; rr < 4; ++rr) {
    int r = wv * 4 + rr;
    float4 va = *(const float4*)&ys[r * 512 + ln * 8];
    float4 vb = *(const float4*)&ys[r * 512 + ln * 8 + 4];
    float s = va.x + va.y + va.z + va.w + vb.x + vb.y + vb.z + vb.w;
    float ss = va.x * va.x + va.y * va.y + va.z * va.z + va.w * va.w +
               vb.x * vb.x + vb.y * vb.y + vb.z * vb.z + vb.w * vb.w;
#pragma unroll
    for (int off = 1; off < 64; off <<= 1) {
      s += __shfl_xor(s, off);
      ss += __shfl_xor(ss, off);
    }
    if (ln == 0) {
      float mean = s * (1.f / 512.f);
      float var = ss * (1.f / 512.f) - mean * mean;
      stats[r][0] = mean;
      stats[r][1] = rsqrtf(var + 1e-5f);
    }
  }
  __syncthreads();

  f32x2 gg = *(const f32x2*)&g2[d0];
  f32x2 bb = *(const f32x2*)&bt2[d0];
  long orow0;
  if (tile < 128) {
    orow0 = ((long)Rr + tile * 16) * Bb + b;
  } else if (tile < 144) {
    orow0 = (long)(32 * (tile - 128)) * Bb + b;
  } else {
    orow0 = (long)(32 * (tile - 144) + 16) * Bb + b;
  }
#pragma unroll
  for (int r = 0; r < 16; ++r) {
    float mean = stats[r][0], rstd = stats[r][1];
    f32x2 y = (acc[r] - mean) * rstd * gg + bb;   // packed
    float z0 = y.x / (1.f + __expf(-y.x));
    float z1 = y.y / (1.f + __expf(-y.y));
    u32 pz = (u32)f2bf(z0) | ((u32)f2bf(z1) << 16);
    *(u32*)&Z[(orow0 + (long)r * Bb) * 512 + d0] = pz;
  }
}

// ---------------- GEMM2 + bias + residual (1-phase BK=64, swizzled LDS,
//                  non-temporal float4 epilogue via LDS retile) ----------------
__global__ __launch_bounds__(256, 4) void k_gemm2(const u16* __restrict__ A,
                                                  const u16* __restrict__ Wb,
                                                  const float* __restrict__ b2,
                                                  const float* __restrict__ utt,
                                                  const float* __restrict__ rc,
                                                  float* __restrict__ out) {
  __shared__ __align__(16) u16 smem[2 * 128 * 64];  // sA | sB; epilogue: 64x128 f32 tile
  u16* sA = smem;
  u16* sB = smem + 128 * 64;
  float* tile = (float*)smem;

  int tid = threadIdx.x;
  int bid = blockIdx.x;
  int bm = bid >> 2, nt = bid & 3;
  long arow0 = (long)bm * 128;
  int ncol0 = nt * 128;
  int lane = tid & 63, wid = tid >> 6;
  int wm = (wid >> 1) * 64, wn = (wid & 1) * 64;
  int lr = lane & 15, kg = lane >> 4;
  int l7 = lr & 7;

  f32x4 acc[4][4];
#pragma unroll
  for (int i = 0; i < 4; ++i)
#pragma unroll
    for (int j = 0; j < 4; ++j) acc[i][j] = (f32x4)0.f;

  for (int k0 = 0; k0 < 512; k0 += 64) {
#pragma unroll
    for (int i = 0; i < 4; ++i) {
      int c = i * 256 + tid;
      int r = c >> 3;
      int col = ((c & 7) ^ (r & 7)) * 8;  // pre-swizzled source column
      load_lds16(A + (arow0 + r) * 512 + k0 + col, &sA[c * 8]);
      load_lds16(Wb + (long)(ncol0 + r) * 512 + k0 + col, &sB[c * 8]);
    }
    __syncthreads();
#pragma unroll
    for (int kf = 0; kf < 2; ++kf) {
      int u = (kf * 4 + kg) ^ l7;  // swizzled read unit
      bf16x8 av[4], bv[4];
#pragma unroll
      for (int i = 0; i < 4; ++i) {
        av[i] = *(const bf16x8*)&sA[(wm + i * 16 + lr) * 64 + u * 8];
        bv[i] = *(const bf16x8*)&sB[(wn + i * 16 + lr) * 64 + u * 8];
      }
#pragma unroll
      for (int mi = 0; mi < 4; ++mi)
#pragma unroll
        for (int ni = 0; ni < 4; ++ni)
          acc[mi][ni] = __builtin_amdgcn_mfma_f32_16x16x32_bf16(
              av[mi], bv[ni], acc[mi][ni], 0, 0, 0);
    }
    __syncthreads();
  }

  // ---- epilogue: two 64-row passes through LDS, nt float4 residual+store ----
  float b2v[4];
#pragma unroll
  for (int ni = 0; ni < 4; ++ni) b2v[ni] = b2[ncol0 + wn + ni * 16 + lr];
  int mg = kg * 4;

#pragma unroll
  for (int p = 0; p < 2; ++p) {
    if ((wid >> 1) == p) {
#pragma unroll
      for (int mi = 0; mi < 4; ++mi)
#pragma unroll
        for (int ni = 0; ni < 4; ++ni)
#pragma unroll
          for (int rgi = 0; rgi < 4; ++rgi) {
            int rl = mi * 16 + mg + rgi;            // 0..63
            int cl = wn + ni * 16 + lr;             // 0..127
            tile[rl * 128 + (cl ^ ((rl & 3) << 3))] = acc[mi][ni][rgi] + b2v[ni];
          }
    }
    __syncthreads();
    long rowbase = arow0 + p * 64;
    bool is_rc = rowbase < 16384;  // block-uniform (arow0 multiple of 128)
#pragma unroll
    for (int rr = 0; rr < 8; ++rr) {
      int idx = rr * 256 + tid;
      int r = idx >> 5, c4 = (idx & 31) << 2;
      f32x4 v = *(const f32x4*)&tile[r * 128 + (c4 ^ ((r & 3) << 3))];
      long row = rowbase + r;
      const float* src;
      float* dst;
      if (is_rc) {
        src = rc + row * 512;
        dst = out + 33554432 + row * 512;
      } else {
        src = utt + (row - 16384) * 512;
        dst = out + (row - 16384) * 512;
      }
      f32x4 rv = __builtin_nontemporal_load((const f32x4*)&src[ncol0 + c4]);
      v += rv;
      __builtin_nontemporal_store(v, (f32x4*)&dst[ncol0 + c4]);
    }
    __syncthreads();
  }
}

extern "C" void kernel_launch(void* const* d_in, const int* in_sizes, int n_in,
                              void* d_out, int out_size, void* d_ws, size_t ws_size,
                              hipStream_t stream) {
  const float* utt = (const float*)d_in[0];
  const float* rc = (const float*)d_in[1];
  const float* state = (const float*)d_in[2];
  const float* ln1g = (const float*)d_in[3];
  const float* ln1b = (const float*)d_in[4];
  const float* w1 = (const float*)d_in[5];
  const float* b1 = (const float*)d_in[6];
  const float* cw = (const float*)d_in[7];
  const float* cb = (const float*)d_in[8];
  const float* ln2g = (const float*)d_in[9];
  const float* ln2b = (const float*)d_in[10];
  const float* w2 = (const float*)d_in[11];
  const float* b2 = (const float*)d_in[12];
  float* out = (float*)d_out;

  char* ws = (char*)d_ws;
  u16* w1b = (u16*)ws;                                         // 1 MB
  u16* w2b = (u16*)(ws + (1 << 20));                           // 512 KB
  float* cwT = (float*)(ws + (1 << 20) + (1 << 19));           // 64 KB
  u16* lnx = (u16*)(ws + (1 << 20) + (1 << 19) + (1 << 16));   // 80 MiB (ln_x, later z)
  u16* xbuf = lnx + (size_t)MROWS * Dm;                        // 80 MiB

  k_cast<<<512, 256, 0, stream>>>(w1, w1b, 1024 * 512);
  k_cast<<<256, 256, 0, stream>>>(w2, w2b, 512 * 512);
  k_wt<<<62, 256, 0, stream>>>(cw, cwT);
  k_ln1<<<MROWS / 4, 256, 0, stream>>>(utt, rc, ln1g, ln1b, lnx);
  k_gemm1<<<2560, 256, 0, stream>>>(lnx, w1b, b1, xbuf);
  k_conv_ln2<<<dim3(160, 32), 256, 0, stream>>>(xbuf, state, cwT, cb, ln2g, ln2b, lnx,
                                                out + 41943040);
  k_gemm2<<<2560, 256, 0, stream>>>(lnx, w2b, b2, utt, rc, out);
}

// Round 23
// 351.370 us; speedup vs baseline: 1.3490x; 1.3490x over previous
//
#include <hip/hip_runtime.h>

// Emformer convolution module, MI355X/gfx950. FINAL (R21 config, 351.4us measured).
// Pipeline: cast weights -> LN1 -> GEMM1+GLU (bf16 MFMA) -> dwconv+LN2+SiLU (+state emit) -> GEMM2+residual.
// Key measured lessons: __syncthreads drains vmcnt(0) (R7); occupancy/TLP beats intra-block dbuf at
// 128^2/2-phase (R8); pre-swizzled-source LDS layout zeroes bank conflicts (R10); conv channel-pairing
// (R12); launch_bounds min-waves squeezes VGPR budget -> spill if live set exceeds 512/waves (R16,R22);
// nt-epilogue + state fusion (R20). Conv split-staging spilled (R22) - reverted.

#define Dm 512
#define STATE 30
#define Uu 2048
#define Rr 512
#define Bb 32
#define Tt 2560        // Rr + Uu
#define MROWS 81920    // Tt * Bb

typedef unsigned short u16;
typedef unsigned int u32;
typedef __attribute__((ext_vector_type(8))) __bf16 bf16x8;
typedef __attribute__((ext_vector_type(4))) float f32x4;
typedef __attribute__((ext_vector_type(2))) float f32x2;

__device__ __forceinline__ u16 f2bf(float x) {
  u32 u = __float_as_uint(x);
  u += 0x7fff + ((u >> 16) & 1);   // RNE
  return (u16)(u >> 16);
}
__device__ __forceinline__ float bf2f(u16 h) {
  return __uint_as_float((u32)h << 16);
}
__device__ __forceinline__ void load_lds16(const void* g, void* l) {
  __builtin_amdgcn_global_load_lds(
      (const __attribute__((address_space(1))) void*)g,
      (__attribute__((address_space(3))) void*)l, 16, 0, 0);
}

// ---------------- cast f32 -> bf16 (weights) ----------------
__global__ __launch_bounds__(256, 4) void k_cast(const float* __restrict__ src,
                                                 u16* __restrict__ dst, int n) {
  int i = (blockIdx.x * 256 + threadIdx.x) * 4;
  if (i >= n) return;
  float4 v = *(const float4*)(src + i);
  u32 lo = (u32)f2bf(v.x) | ((u32)f2bf(v.y) << 16);
  u32 hi = (u32)f2bf(v.z) | ((u32)f2bf(v.w) << 16);
  *(uint2*)(dst + i) = make_uint2(lo, hi);
}

// ---------------- transpose conv weight: cw[512][31] -> cwT[31][512] ----------------
__global__ __launch_bounds__(256, 4) void k_wt(const float* __restrict__ cw,
                                               float* __restrict__ cwT) {
  int i = blockIdx.x * 256 + threadIdx.x;
  if (i >= 31 * 512) return;
  int k = i >> 9, d = i & 511;
  cwT[i] = cw[d * 31 + k];
}

// ---------------- LN1: concat(rc, utt) -> bf16 ----------------
__global__ __launch_bounds__(256, 4) void k_ln1(const float* __restrict__ utt,
                                                const float* __restrict__ rc,
                                                const float* __restrict__ g,
                                                const float* __restrict__ b,
                                                u16* __restrict__ out) {
  int wid = threadIdx.x >> 6, lane = threadIdx.x & 63;
  long row = (long)blockIdx.x * 4 + wid;  // token index tau = t*B + b
  const float* src = (row < (long)Rr * Bb) ? rc + row * Dm
                                           : utt + (row - (long)Rr * Bb) * Dm;
  int d0 = lane * 8;
  float4 v0 = *(const float4*)(src + d0);
  float4 v1 = *(const float4*)(src + d0 + 4);
  float s = v0.x + v0.y + v0.z + v0.w + v1.x + v1.y + v1.z + v1.w;
  float ss = v0.x * v0.x + v0.y * v0.y + v0.z * v0.z + v0.w * v0.w +
             v1.x * v1.x + v1.y * v1.y + v1.z * v1.z + v1.w * v1.w;
#pragma unroll
  for (int off = 1; off < 64; off <<= 1) {
    s += __shfl_xor(s, off);
    ss += __shfl_xor(ss, off);
  }
  float mean = s * (1.f / 512.f);
  float var = ss * (1.f / 512.f) - mean * mean;
  float rstd = rsqrtf(var + 1e-5f);
  float4 g0 = *(const float4*)(g + d0);
  float4 g1 = *(const float4*)(g + d0 + 4);
  float4 b0 = *(const float4*)(b + d0);
  float4 b1v = *(const float4*)(b + d0 + 4);
  float o[8];
  o[0] = (v0.x - mean) * rstd * g0.x + b0.x;
  o[1] = (v0.y - mean) * rstd * g0.y + b0.y;
  o[2] = (v0.z - mean) * rstd * g0.z + b0.z;
  o[3] = (v0.w - mean) * rstd * g0.w + b0.w;
  o[4] = (v1.x - mean) * rstd * g1.x + b1v.x;
  o[5] = (v1.y - mean) * rstd * g1.y + b1v.y;
  o[6] = (v1.z - mean) * rstd * g1.z + b1v.z;
  o[7] = (v1.w - mean) * rstd * g1.w + b1v.w;
  u32 p[4];
#pragma unroll
  for (int i = 0; i < 4; ++i)
    p[i] = (u32)f2bf(o[2 * i]) | ((u32)f2bf(o[2 * i + 1]) << 16);
  *(uint4*)(out + row * Dm + d0) = make_uint4(p[0], p[1], p[2], p[3]);
}

// ---------------- GEMM1 + GLU (1-phase BK=64, swizzled LDS) ----------------
__global__ __launch_bounds__(256, 2) void k_gemm1(const u16* __restrict__ A,
                                                  const u16* __restrict__ Wb,
                                                  const float* __restrict__ b1,
                                                  u16* __restrict__ X) {
  __shared__ __align__(16) u16 sA[128 * 64], sBa[128 * 64], sBg[128 * 64];
  int tid = threadIdx.x;
  int bid = blockIdx.x;
  int bm = bid >> 2, nt = bid & 3;
  long arow0 = (long)bm * 128;
  int ncol0 = nt * 128;
  int lane = tid & 63, wid = tid >> 6;
  int wm = (wid >> 1) * 64, wn = (wid & 1) * 64;
  int lr = lane & 15, kg = lane >> 4;
  int l7 = lr & 7;

  f32x4 acc_a[4][4], acc_g[4][4];
#pragma unroll
  for (int i = 0; i < 4; ++i)
#pragma unroll
    for (int j = 0; j < 4; ++j) {
      acc_a[i][j] = (f32x4)0.f;
      acc_g[i][j] = (f32x4)0.f;
    }

  for (int k0 = 0; k0 < 512; k0 += 64) {
#pragma unroll
    for (int i = 0; i < 4; ++i) {
      int c = i * 256 + tid;
      int r = c >> 3;
      int col = ((c & 7) ^ (r & 7)) * 8;  // pre-swizzled source column
      load_lds16(A + (arow0 + r) * 512 + k0 + col, &sA[c * 8]);
      load_lds16(Wb + (long)(ncol0 + r) * 512 + k0 + col, &sBa[c * 8]);
      load_lds16(Wb + (long)(512 + ncol0 + r) * 512 + k0 + col, &sBg[c * 8]);
    }
    __syncthreads();
#pragma unroll
    for (int kf = 0; kf < 2; ++kf) {
      int u = (kf * 4 + kg) ^ l7;  // swizzled read unit
      bf16x8 av[4], bav[4], bgv[4];
#pragma unroll
      for (int i = 0; i < 4; ++i) {
        av[i] = *(const bf16x8*)&sA[(wm + i * 16 + lr) * 64 + u * 8];
        bav[i] = *(const bf16x8*)&sBa[(wn + i * 16 + lr) * 64 + u * 8];
        bgv[i] = *(const bf16x8*)&sBg[(wn + i * 16 + lr) * 64 + u * 8];
      }
#pragma unroll
      for (int mi = 0; mi < 4; ++mi)
#pragma unroll
        for (int ni = 0; ni < 4; ++ni) {
          acc_a[mi][ni] = __builtin_amdgcn_mfma_f32_16x16x32_bf16(
              av[mi], bav[ni], acc_a[mi][ni], 0, 0, 0);
          acc_g[mi][ni] = __builtin_amdgcn_mfma_f32_16x16x32_bf16(
              av[mi], bgv[ni], acc_g[mi][ni], 0, 0, 0);
        }
    }
    __syncthreads();
  }
  int mg = kg * 4;
#pragma unroll
  for (int mi = 0; mi < 4; ++mi) {
#pragma unroll
    for (int ni = 0; ni < 4; ++ni) {
      int ncol = ncol0 + wn + ni * 16 + lr;
      float ba = b1[ncol], bg = b1[512 + ncol];
#pragma unroll
      for (int rgi = 0; rgi < 4; ++rgi) {
        long row = arow0 + wm + mi * 16 + mg + rgi;
        float a = acc_a[mi][ni][rgi] + ba;
        float gg = acc_g[mi][ni][rgi] + bg;
        float val = a / (1.f + __expf(-gg));
        X[row * 512 + ncol] = f2bf(val);
      }
    }
  }
}

// ---------------- depthwise conv + LN2 + SiLU + state emit ----------------
// grid (160, 32), 256 threads: thread t owns channels {2t, 2t+1}. Packed f32x2 math.
// tile==127 blocks also emit new_state (X trows 2530..2559 = staged rows 16..45).
__global__ __launch_bounds__(256, 3) void k_conv_ln2(
    const u16* __restrict__ X, const float* __restrict__ state,
    const float* __restrict__ cwT, const float* __restrict__ cb,
    const float* __restrict__ g2, const float* __restrict__ bt2,
    u16* __restrict__ Z, float* __restrict__ st_out) {
  __shared__ __align__(16) u16 stX[46 * 512];   // 47104 B; later aliased as ys[16][512] f32
  __shared__ float stats[16][2];
  float* ys = (float*)stX;

  int t = threadIdx.x;            // 0..255
  int d0 = t * 2;                 // channel pair
  int tile = blockIdx.x, b = blockIdx.y;
  int wv = t >> 6, ln = t & 63;   // 4 waves

  f32x2 w[31];
#pragma unroll
  for (int k = 0; k < 31; ++k) w[k] = *(const f32x2*)&cwT[k * 512 + d0];  // coalesced
  f32x2 acc[16];
  {
    f32x2 cb2 = *(const f32x2*)&cb[d0];
#pragma unroll
    for (int r = 0; r < 16; ++r) acc[r] = cb2;
  }

  auto step = [&](int j, f32x2 x) {
#pragma unroll
    for (int r = 0; r < 16; ++r) {
      int k = j - r;
      if (k >= 0 && k < 31) acc[r] += x * w[k];   // packed fma
    }
  };
  auto unpack = [](u32 xx) -> f32x2 {
    f32x2 v;
    v.x = __uint_as_float(xx << 16);
    v.y = __uint_as_float(xx & 0xffff0000u);
    return v;
  };

  const u16* Xb = X + (long)b * 512;  // + trow*16384 + col

  if (tile >= 2) {
    // ---- stage 46 rows (1KB each); wave wv does rows wv, wv+4, ... ----
    if (tile < 128) {
      long base = (long)Rr + tile * 16 - 30;
      for (int r = wv; r < 46; r += 4)
        load_lds16(Xb + (base + r) * 16384 + ln * 8, &stX[r * 512 + ln * 8]);
    } else if (tile < 144) {
      int s = tile - 128;
      for (int r = wv; r < 46; r += 4) {
        long trow = (r < 30) ? ((long)Rr + 128 * (s + 1) - 30 + r)
                             : ((long)32 * s + r - 30);
        load_lds16(Xb + trow * 16384 + ln * 8, &stX[r * 512 + ln * 8]);
      }
    } else {
      int s = tile - 144;
      for (int r = wv; r < 46; r += 4) {
        long trow = (r < 14) ? ((long)Rr + 128 * (s + 1) - 14 + r)
                             : ((long)32 * s + r - 14);
        load_lds16(Xb + trow * 16384 + ln * 8, &stX[r * 512 + ln * 8]);
      }
    }
    __syncthreads();
    // ---- consume: one b32 per j -> 2 channels; static offsets ----
#pragma unroll
    for (int j = 0; j < 46; ++j) {
      u32 xx = *(const u32*)&stX[j * 512 + d0];
      step(j, unpack(xx));
      if ((j & 7) == 7) __builtin_amdgcn_sched_barrier(0);
    }
    // ---- tile 127: emit new_state from staged rows 16..45 (before ys aliases stX) ----
    if (tile == 127) {
      float* s0 = st_out + ((long)b * 512 + d0) * 30;
      float* s1 = s0 + 30;
#pragma unroll
      for (int j = 0; j < 30; ++j) {
        u32 xx = *(const u32*)&stX[(16 + j) * 512 + d0];
        s0[j] = __uint_as_float(xx << 16);
        s1[j] = __uint_as_float(xx & 0xffff0000u);
      }
    }
  } else {
    // tiles 0..1: window reaches before utterance start
    long t0 = (long)tile * 16;
    const float* st0 = state + ((long)b * 512 + d0) * 30;
    const float* st1 = st0 + 30;
    const u16* Xc = Xb + d0;
#pragma unroll
    for (int j = 0; j < 46; ++j) {
      long tj = t0 - 30 + j;
      f32x2 x;
      if (tj < 0) {
        x.x = st0[tj + 30];
        x.y = st1[tj + 30];
      } else {
        x = unpack(*(const u32*)&Xc[((long)Rr + tj) * 16384]);
      }
      step(j, x);
      if ((j & 15) == 15) __builtin_amdgcn_sched_barrier(0);
    }
  }

  __syncthreads();  // all stX reads done before ys overwrites it
#pragma unroll
  for (int r = 0; r < 16; ++r) {
    *(f32x2*)&ys[r * 512 + d0] = acc[r];
  }
  __syncthreads();

#pragma unroll
  for (int rr = 0; rr < 4; ++rr) {
    int r = wv * 4 + rr;
    float4 va = *(const float4*)&ys[r * 512 + ln * 8];
    float4 vb = *(const float4*)&ys[r * 512 + ln * 8 + 4];
    float s = va.x + va.y + va.z + va.w + vb.x + vb.y + vb.z + vb.w;
    float ss = va.x * va.x + va.y * va.y + va.z * va.z + va.w * va.w +
               vb.x * vb.x + vb.y * vb.y + vb.z * vb.z + vb.w * vb.w;
#pragma unroll
    for (int off = 1; off < 64; off <<= 1) {
      s += __shfl_xor(s, off);
      ss += __shfl_xor(ss, off);
    }
    if (ln == 0) {
      float mean = s * (1.f / 512.f);
      float var = ss * (1.f / 512.f) - mean * mean;
      stats[r][0] = mean;
      stats[r][1] = rsqrtf(var + 1e-5f);
    }
  }
  __syncthreads();

  f32x2 gg = *(const f32x2*)&g2[d0];
  f32x2 bb = *(const f32x2*)&bt2[d0];
  long orow0;
  if (tile < 128) {
    orow0 = ((long)Rr + tile * 16) * Bb + b;
  } else if (tile < 144) {
    orow0 = (long)(32 * (tile - 128)) * Bb + b;
  } else {
    orow0 = (long)(32 * (tile - 144) + 16) * Bb + b;
  }
#pragma unroll
  for (int r = 0; r < 16; ++r) {
    float mean = stats[r][0], rstd = stats[r][1];
    f32x2 y = (acc[r] - mean) * rstd * gg + bb;   // packed
    float z0 = y.x / (1.f + __expf(-y.x));
    float z1 = y.y / (1.f + __expf(-y.y));
    u32 pz = (u32)f2bf(z0) | ((u32)f2bf(z1) << 16);
    *(u32*)&Z[(orow0 + (long)r * Bb) * 512 + d0] = pz;
  }
}

// ---------------- GEMM2 + bias + residual (1-phase BK=64, swizzled LDS,
//                  non-temporal float4 epilogue via LDS retile) ----------------
__global__ __launch_bounds__(256, 4) void k_gemm2(const u16* __restrict__ A,
                                                  const u16* __restrict__ Wb,
                                                  const float* __restrict__ b2,
                                                  const float* __restrict__ utt,
                                                  const float* __restrict__ rc,
                                                  float* __restrict__ out) {
  __shared__ __align__(16) u16 smem[2 * 128 * 64];  // sA | sB; epilogue: 64x128 f32 tile
  u16* sA = smem;
  u16* sB = smem + 128 * 64;
  float* tile = (float*)smem;

  int tid = threadIdx.x;
  int bid = blockIdx.x;
  int bm = bid >> 2, nt = bid & 3;
  long arow0 = (long)bm * 128;
  int ncol0 = nt * 128;
  int lane = tid & 63, wid = tid >> 6;
  int wm = (wid >> 1) * 64, wn = (wid & 1) * 64;
  int lr = lane & 15, kg = lane >> 4;
  int l7 = lr & 7;

  f32x4 acc[4][4];
#pragma unroll
  for (int i = 0; i < 4; ++i)
#pragma unroll
    for (int j = 0; j < 4; ++j) acc[i][j] = (f32x4)0.f;

  for (int k0 = 0; k0 < 512; k0 += 64) {
#pragma unroll
    for (int i = 0; i < 4; ++i) {
      int c = i * 256 + tid;
      int r = c >> 3;
      int col = ((c & 7) ^ (r & 7)) * 8;  // pre-swizzled source column
      load_lds16(A + (arow0 + r) * 512 + k0 + col, &sA[c * 8]);
      load_lds16(Wb + (long)(ncol0 + r) * 512 + k0 + col, &sB[c * 8]);
    }
    __syncthreads();
#pragma unroll
    for (int kf = 0; kf < 2; ++kf) {
      int u = (kf * 4 + kg) ^ l7;  // swizzled read unit
      bf16x8 av[4], bv[4];
#pragma unroll
      for (int i = 0; i < 4; ++i) {
        av[i] = *(const bf16x8*)&sA[(wm + i * 16 + lr) * 64 + u * 8];
        bv[i] = *(const bf16x8*)&sB[(wn + i * 16 + lr) * 64 + u * 8];
      }
#pragma unroll
      for (int mi = 0; mi < 4; ++mi)
#pragma unroll
        for (int ni = 0; ni < 4; ++ni)
          acc[mi][ni] = __builtin_amdgcn_mfma_f32_16x16x32_bf16(
              av[mi], bv[ni], acc[mi][ni], 0, 0, 0);
    }
    __syncthreads();
  }

  // ---- epilogue: two 64-row passes through LDS, nt float4 residual+store ----
  float b2v[4];
#pragma unroll
  for (int ni = 0; ni < 4; ++ni) b2v[ni] = b2[ncol0 + wn + ni * 16 + lr];
  int mg = kg * 4;

#pragma unroll
  for (int p = 0; p < 2; ++p) {
    if ((wid >> 1) == p) {
#pragma unroll
      for (int mi = 0; mi < 4; ++mi)
#pragma unroll
        for (int ni = 0; ni < 4; ++ni)
#pragma unroll
          for (int rgi = 0; rgi < 4; ++rgi) {
            int rl = mi * 16 + mg + rgi;            // 0..63
            int cl = wn + ni * 16 + lr;             // 0..127
            tile[rl * 128 + (cl ^ ((rl & 3) << 3))] = acc[mi][ni][rgi] + b2v[ni];
          }
    }
    __syncthreads();
    long rowbase = arow0 + p * 64;
    bool is_rc = rowbase < 16384;  // block-uniform (arow0 multiple of 128)
#pragma unroll
    for (int rr = 0; rr < 8; ++rr) {
      int idx = rr * 256 + tid;
      int r = idx >> 5, c4 = (idx & 31) << 2;
      f32x4 v = *(const f32x4*)&tile[r * 128 + (c4 ^ ((r & 3) << 3))];
      long row = rowbase + r;
      const float* src;
      float* dst;
      if (is_rc) {
        src = rc + row * 512;
        dst = out + 33554432 + row * 512;
      } else {
        src = utt + (row - 16384) * 512;
        dst = out + (row - 16384) * 512;
      }
      f32x4 rv = __builtin_nontemporal_load((const f32x4*)&src[ncol0 + c4]);
      v += rv;
      __builtin_nontemporal_store(v, (f32x4*)&dst[ncol0 + c4]);
    }
    __syncthreads();
  }
}

extern "C" void kernel_launch(void* const* d_in, const int* in_sizes, int n_in,
                              void* d_out, int out_size, void* d_ws, size_t ws_size,
                              hipStream_t stream) {
  const float* utt = (const float*)d_in[0];
  const float* rc = (const float*)d_in[1];
  const float* state = (const float*)d_in[2];
  const float* ln1g = (const float*)d_in[3];
  const float* ln1b = (const float*)d_in[4];
  const float* w1 = (const float*)d_in[5];
  const float* b1 = (const float*)d_in[6];
  const float* cw = (const float*)d_in[7];
  const float* cb = (const float*)d_in[8];
  const float* ln2g = (const float*)d_in[9];
  const float* ln2b = (const float*)d_in[10];
  const float* w2 = (const float*)d_in[11];
  const float* b2 = (const float*)d_in[12];
  float* out = (float*)d_out;

  char* ws = (char*)d_ws;
  u16* w1b = (u16*)ws;                                         // 1 MB
  u16* w2b = (u16*)(ws + (1 << 20));                           // 512 KB
  float* cwT = (float*)(ws + (1 << 20) + (1 << 19));           // 64 KB
  u16* lnx = (u16*)(ws + (1 << 20) + (1 << 19) + (1 << 16));   // 80 MiB (ln_x, later z)
  u16* xbuf = lnx + (size_t)MROWS * Dm;                        // 80 MiB

  k_cast<<<512, 256, 0, stream>>>(w1, w1b, 1024 * 512);
  k_cast<<<256, 256, 0, stream>>>(w2, w2b, 512 * 512);
  k_wt<<<62, 256, 0, stream>>>(cw, cwT);
  k_ln1<<<MROWS / 4, 256, 0, stream>>>(utt, rc, ln1g, ln1b, lnx);
  k_gemm1<<<2560, 256, 0, stream>>>(lnx, w1b, b1, xbuf);
  k_conv_ln2<<<dim3(160, 32), 256, 0, stream>>>(xbuf, state, cwT, cb, ln2g, ln2b, lnx,
                                                out + 41943040);
  k_gemm2<<<2560, 256, 0, stream>>>(lnx, w2b, b2, utt, rc, out);
}